// Round 2
// baseline (384.874 us; speedup 1.0000x reference)
//
#include <hip/hip_runtime.h>

typedef unsigned short u16;
typedef __bf16 bf16x8_t __attribute__((ext_vector_type(8)));
typedef float f32x4_t __attribute__((ext_vector_type(4)));

#define T_SEQ 4096
#define EMB 512
#define NH 8
#define NKV 2
#define HD 64

__device__ __forceinline__ float bf2f(u16 h) {
    union { unsigned u; float f; } x; x.u = ((unsigned)h) << 16; return x.f;
}
__device__ __forceinline__ u16 f2bf(float f) {
    union { float f; unsigned u; } x; x.f = f;
    unsigned r = x.u + 0x7FFFu + ((x.u >> 16) & 1u);
    return (u16)(r >> 16);
}

// ------------- weight transpose + cast: W[K][N] (f32) -> WT[N][K] (bf16) -------------
__global__ void transpose_kernel(const float* __restrict__ W, u16* __restrict__ WT,
                                 int K, int N) {
    int i = blockIdx.x * 256 + threadIdx.x;
    if (i < K * N) {
        int n = i / K;
        int k = i - n * K;
        WT[i] = f2bf(W[(size_t)k * N + n]);
    }
}

// ------------- x cast: f32 -> bf16, 4 elems/thread -------------
__global__ void cvt_kernel(const float* __restrict__ in, u16* __restrict__ out, int n4) {
    int i = blockIdx.x * 256 + threadIdx.x;
    if (i < n4) {
        float4 v = *reinterpret_cast<const float4*>(in + (size_t)i * 4);
        u16 o[4] = { f2bf(v.x), f2bf(v.y), f2bf(v.z), f2bf(v.w) };
        *reinterpret_cast<uint2*>(out + (size_t)i * 4) = *reinterpret_cast<uint2*>(o);
    }
}

// ------------- RoPE tables: cos/sin[t][j], j<32, fp32 (double trig ~= np ref) -------------
__global__ void rope_table_kernel(float* __restrict__ cost, float* __restrict__ sint) {
    int i = blockIdx.x * 256 + threadIdx.x;   // T_SEQ*32 total
    int t = i >> 5, j = i & 31;
    double invf = pow(1.0e6, -(double)j / 32.0);
    double ang = (double)t * invf;
    cost[i] = (float)cos(ang);
    sint[i] = (float)sin(ang);
}

// ---------------- GEMM: C[M,N] = A[M,K](bf16) @ Bt[N,K](bf16)^T ----------------
// EPI=0: fp32 store to C.  EPI=1: bias + RoPE + scale-q + scatter to q/k/v (bf16).
template <int EPI>
__global__ __launch_bounds__(256)
void gemm_kernel(const u16* __restrict__ A, const u16* __restrict__ Bt, int K,
                 float* __restrict__ C, int N,
                 const float* __restrict__ bq, const float* __restrict__ bk,
                 const float* __restrict__ bv,
                 const float* __restrict__ cost, const float* __restrict__ sint,
                 u16* __restrict__ qw, u16* __restrict__ kw, u16* __restrict__ vw)
{
    __shared__ __align__(16) u16 As[128][72];   // +8 pad: 2-way bank alias (free)
    __shared__ __align__(16) u16 Bs[128][72];

    const int tid  = threadIdx.x;
    const int lane = tid & 63, wave = tid >> 6;
    const int wr = wave >> 1, wc = wave & 1;    // 2x2 waves over 128x128
    const int tm = blockIdx.x, tn = blockIdx.y;
    const int lrow = lane & 15, lgrp = lane >> 4;

    f32x4_t acc[4][4];
#pragma unroll
    for (int i = 0; i < 4; ++i)
#pragma unroll
        for (int j = 0; j < 4; ++j) acc[i][j] = (f32x4_t){0.f, 0.f, 0.f, 0.f};

    for (int k0 = 0; k0 < K; k0 += 64) {
        __syncthreads();
        {
            const int r0 = tid >> 3;
            const int ko = (tid & 7) * 8;
#pragma unroll
            for (int rr = 0; rr < 4; ++rr) {
                int row = r0 + rr * 32;
                uint4 va = *reinterpret_cast<const uint4*>(A + (size_t)(tm * 128 + row) * K + k0 + ko);
                *reinterpret_cast<uint4*>(&As[row][ko]) = va;
                uint4 vb = *reinterpret_cast<const uint4*>(Bt + (size_t)(tn * 128 + row) * K + k0 + ko);
                *reinterpret_cast<uint4*>(&Bs[row][ko]) = vb;
            }
        }
        __syncthreads();
#pragma unroll
        for (int kc = 0; kc < 2; ++kc) {
            bf16x8_t af[4], bf[4];
#pragma unroll
            for (int mb = 0; mb < 4; ++mb)
                af[mb] = *reinterpret_cast<const bf16x8_t*>(&As[wr * 64 + mb * 16 + lrow][kc * 32 + lgrp * 8]);
#pragma unroll
            for (int nb = 0; nb < 4; ++nb)
                bf[nb] = *reinterpret_cast<const bf16x8_t*>(&Bs[wc * 64 + nb * 16 + lrow][kc * 32 + lgrp * 8]);
#pragma unroll
            for (int mb = 0; mb < 4; ++mb)
#pragma unroll
                for (int nb = 0; nb < 4; ++nb)
                    acc[mb][nb] = __builtin_amdgcn_mfma_f32_16x16x32_bf16(af[mb], bf[nb], acc[mb][nb], 0, 0, 0);
        }
    }

    if (EPI == 0) {
#pragma unroll
        for (int mb = 0; mb < 4; ++mb)
#pragma unroll
            for (int nb = 0; nb < 4; ++nb)
#pragma unroll
                for (int r = 0; r < 4; ++r) {
                    int row = tm * 128 + wr * 64 + mb * 16 + lgrp * 4 + r;
                    int col = tn * 128 + wc * 64 + nb * 16 + lrow;
                    C[(size_t)row * N + col] = acc[mb][nb][r];
                }
    } else {
        // QKV epilogue: bias + RoPE (+0.125 scale on q) + scatter.
        // Pair (d, d+32) lives in acc[mb][nb] / acc[mb][nb+2] for nb in {0,1}.
#pragma unroll
        for (int mb = 0; mb < 4; ++mb)
#pragma unroll
            for (int r = 0; r < 4; ++r) {
                int grow = tm * 128 + wr * 64 + mb * 16 + lgrp * 4 + r;
                int b = grow >> 12, t = grow & 4095;
#pragma unroll
                for (int nb = 0; nb < 2; ++nb) {
                    int n = tn * 128 + wc * 64 + nb * 16 + lrow;  // low column of pair
                    int j = n & 63;                               // < 32 by construction
                    float c0 = acc[mb][nb][r];
                    float c1 = acc[mb][nb + 2][r];
                    if (n < 512) {               // Q
                        c0 += bq[n]; c1 += bq[n + 32];
                        float cs = cost[t * 32 + j], sn = sint[t * 32 + j];
                        float r0 = c0 * cs - c1 * sn;
                        float r1 = c1 * cs + c0 * sn;
                        r0 *= 0.125f; r1 *= 0.125f;   // fold HEAD_DIM^-0.5 into q
                        int h = n >> 6;
                        size_t base = ((size_t)(b * NH + h) * T_SEQ + t) * HD;
                        qw[base + j]      = f2bf(r0);
                        qw[base + j + 32] = f2bf(r1);
                    } else if (n < 640) {        // K
                        int nn = n - 512;
                        c0 += bk[nn]; c1 += bk[nn + 32];
                        float cs = cost[t * 32 + j], sn = sint[t * 32 + j];
                        float r0 = c0 * cs - c1 * sn;
                        float r1 = c1 * cs + c0 * sn;
                        int hk2 = nn >> 6;
                        size_t base = ((size_t)(b * NKV + hk2) * T_SEQ + t) * HD;
                        kw[base + j]      = f2bf(r0);
                        kw[base + j + 32] = f2bf(r1);
                    } else {                     // V (no RoPE)
                        int nn = n - 640;
                        c0 += bv[nn]; c1 += bv[nn + 32];
                        int hv = nn >> 6;
                        size_t base = ((size_t)(b * NKV + hv) * T_SEQ + t) * HD;
                        vw[base + j]      = f2bf(c0);
                        vw[base + j + 32] = f2bf(c1);
                    }
                }
            }
    }
}

// ---------------- causal flash attention (all bf16 in ws) ----------------
// grid: (T/64, B*NH). block: 256 threads = 4 waves, wave w owns q-rows [w*16, w*16+16).
__global__ __launch_bounds__(256)
void attn_kernel(const u16* __restrict__ qw, const u16* __restrict__ kw,
                 const u16* __restrict__ vw, u16* __restrict__ ao)
{
    __shared__ __align__(16) u16 Ks[64][72];   // [s][d]
    __shared__ __align__(16) u16 Vs[64][72];   // transposed: [d][s]
    __shared__ __align__(16) u16 Ps[64][72];   // [qrow][s] bf16 P

    const int qt = blockIdx.x;
    const int hdix = blockIdx.y;
    const int b = hdix >> 3, h = hdix & 7, hk = h >> 2;
    const int tid = threadIdx.x, lane = tid & 63, wave = tid >> 6;
    const int lrow = lane & 15, lgrp = lane >> 4;

    const u16* qbase = qw + ((size_t)(b * NH + h) * T_SEQ + qt * 64) * HD;
    const u16* kbase = kw + (size_t)(b * NKV + hk) * T_SEQ * HD;
    const u16* vbase = vw + (size_t)(b * NKV + hk) * T_SEQ * HD;

    // Q fragments held in registers for the whole kernel (scale pre-folded).
    bf16x8_t qf[2];
#pragma unroll
    for (int kc = 0; kc < 2; ++kc)
        qf[kc] = *reinterpret_cast<const bf16x8_t*>(qbase + (wave * 16 + lrow) * HD + kc * 32 + lgrp * 8);

    float m[4], l[4];
    f32x4_t o[4];
#pragma unroll
    for (int r = 0; r < 4; ++r) { m[r] = -1e30f; l[r] = 0.f; }
#pragma unroll
    for (int d = 0; d < 4; ++d) o[d] = (f32x4_t){0.f, 0.f, 0.f, 0.f};

    for (int kt = 0; kt <= qt; ++kt) {
        __syncthreads();   // previous iteration's LDS reads done
        {
            const int r0 = tid >> 3;        // 0..31
            const int co = (tid & 7) * 8;   // 0..56
#pragma unroll
            for (int rr = 0; rr < 2; ++rr) {
                int s = r0 + rr * 32;
                uint4 vk = *reinterpret_cast<const uint4*>(kbase + (size_t)(kt * 64 + s) * HD + co);
                *reinterpret_cast<uint4*>(&Ks[s][co]) = vk;
                uint4 vv = *reinterpret_cast<const uint4*>(vbase + (size_t)(kt * 64 + s) * HD + co);
                const u16* pv = reinterpret_cast<const u16*>(&vv);
#pragma unroll
                for (int jj = 0; jj < 8; ++jj) Vs[co + jj][s] = pv[jj];
            }
        }
        __syncthreads();

        // S = q @ k^T  (scale already folded into q)
        f32x4_t sacc[4];
#pragma unroll
        for (int kb = 0; kb < 4; ++kb) sacc[kb] = (f32x4_t){0.f, 0.f, 0.f, 0.f};
#pragma unroll
        for (int kc = 0; kc < 2; ++kc)
#pragma unroll
            for (int kb = 0; kb < 4; ++kb) {
                bf16x8_t kf = *reinterpret_cast<const bf16x8_t*>(&Ks[kb * 16 + lrow][kc * 32 + lgrp * 8]);
                sacc[kb] = __builtin_amdgcn_mfma_f32_16x16x32_bf16(qf[kc], kf, sacc[kb], 0, 0, 0);
            }

        if (kt == qt) {   // causal mask only on diagonal tile
#pragma unroll
            for (int kb = 0; kb < 4; ++kb)
#pragma unroll
                for (int r = 0; r < 4; ++r) {
                    int qr = wave * 16 + lgrp * 4 + r;
                    int kc2 = kb * 16 + lrow;
                    if (kc2 > qr) sacc[kb][r] = -1e30f;
                }
        }

        // online softmax: rows live in 16-lane groups
        float al[4];
#pragma unroll
        for (int r = 0; r < 4; ++r) {
            float v = fmaxf(fmaxf(sacc[0][r], sacc[1][r]), fmaxf(sacc[2][r], sacc[3][r]));
#pragma unroll
            for (int off = 1; off < 16; off <<= 1) v = fmaxf(v, __shfl_xor(v, off));
            float mn = fmaxf(m[r], v);
            al[r] = __expf(m[r] - mn);
            m[r] = mn;
        }
        float p[4][4];
#pragma unroll
        for (int kb = 0; kb < 4; ++kb)
#pragma unroll
            for (int r = 0; r < 4; ++r) p[kb][r] = __expf(sacc[kb][r] - m[r]);
#pragma unroll
        for (int r = 0; r < 4; ++r) {
            float v = p[0][r] + p[1][r] + p[2][r] + p[3][r];
#pragma unroll
            for (int off = 1; off < 16; off <<= 1) v += __shfl_xor(v, off);
            l[r] = l[r] * al[r] + v;
        }
#pragma unroll
        for (int d = 0; d < 4; ++d)
#pragma unroll
            for (int r = 0; r < 4; ++r) o[d][r] *= al[r];

        // P -> LDS (bf16), per-wave disjoint rows
#pragma unroll
        for (int kb = 0; kb < 4; ++kb)
#pragma unroll
            for (int r = 0; r < 4; ++r)
                Ps[wave * 16 + lgrp * 4 + r][kb * 16 + lrow] = f2bf(p[kb][r]);
        __syncthreads();

        // O += P @ V
#pragma unroll
        for (int kc = 0; kc < 2; ++kc) {
            bf16x8_t pf = *reinterpret_cast<const bf16x8_t*>(&Ps[wave * 16 + lrow][kc * 32 + lgrp * 8]);
#pragma unroll
            for (int d = 0; d < 4; ++d) {
                bf16x8_t vf = *reinterpret_cast<const bf16x8_t*>(&Vs[d * 16 + lrow][kc * 32 + lgrp * 8]);
                o[d] = __builtin_amdgcn_mfma_f32_16x16x32_bf16(pf, vf, o[d], 0, 0, 0);
            }
        }
    }

    // epilogue: normalize and store [B,T,H*D] (bf16)
#pragma unroll
    for (int d = 0; d < 4; ++d)
#pragma unroll
        for (int r = 0; r < 4; ++r) {
            int t = qt * 64 + wave * 16 + lgrp * 4 + r;
            float inv = 1.0f / l[r];
            ao[((size_t)(b * T_SEQ) + t) * EMB + h * HD + d * 16 + lrow] = f2bf(o[d][r] * inv);
        }
}

// ---------------- launch ----------------
extern "C" void kernel_launch(void* const* d_in, const int* in_sizes, int n_in,
                              void* d_out, int out_size, void* d_ws, size_t ws_size,
                              hipStream_t stream)
{
    const float* x  = (const float*)d_in[0];
    const float* Wq = (const float*)d_in[1];
    const float* bq = (const float*)d_in[2];
    const float* Wk = (const float*)d_in[3];
    const float* bk = (const float*)d_in[4];
    const float* Wv = (const float*)d_in[5];
    const float* bv = (const float*)d_in[6];
    const float* Wo = (const float*)d_in[7];
    float* out = (float*)d_out;

    char* ws = (char*)d_ws;
    u16*   WqkvT = (u16*)(ws);                  // [768][512] bf16
    u16*   WoT   = (u16*)(ws + 786432);         // [512][512] bf16
    float* cost  = (float*)(ws + 1310720);      // [4096][32] f32
    float* sint  = (float*)(ws + 1835008);      // [4096][32] f32
    u16*   xbf   = (u16*)(ws + 2359296);        // [8192][512] bf16
    u16*   qw    = (u16*)(ws + 10747904);       // [2][8][4096][64] bf16 (pre-scaled)
    u16*   kw    = (u16*)(ws + 19136512);       // [2][2][4096][64] bf16
    u16*   vw    = (u16*)(ws + 21233664);       // [2][2][4096][64] bf16
    u16*   ao    = (u16*)(ws + 23330816);       // [8192][512] bf16   (ends 31719424)

    transpose_kernel<<<(512 * 512 + 255) / 256, 256, 0, stream>>>(Wq, WqkvT, 512, 512);
    transpose_kernel<<<(512 * 128 + 255) / 256, 256, 0, stream>>>(Wk, WqkvT + 512 * 512, 512, 128);
    transpose_kernel<<<(512 * 128 + 255) / 256, 256, 0, stream>>>(Wv, WqkvT + 640 * 512, 512, 128);
    transpose_kernel<<<(512 * 512 + 255) / 256, 256, 0, stream>>>(Wo, WoT, 512, 512);
    cvt_kernel<<<(2 * T_SEQ * EMB / 4 + 255) / 256, 256, 0, stream>>>(x, xbf, 2 * T_SEQ * EMB / 4);
    rope_table_kernel<<<(T_SEQ * 32) / 256, 256, 0, stream>>>(cost, sint);

    dim3 gp(64, 6);   // M/128 x 768/128
    gemm_kernel<1><<<gp, 256, 0, stream>>>(xbf, WqkvT, 512, nullptr, 768,
                                           bq, bk, bv, cost, sint, qw, kw, vw);

    dim3 ga(T_SEQ / 64, 2 * NH);
    attn_kernel<<<ga, 256, 0, stream>>>(qw, kw, vw, ao);

    dim3 go(64, 4);   // M/128 x 512/128
    gemm_kernel<0><<<go, 256, 0, stream>>>(ao, WoT, 512, out, 512,
                                           nullptr, nullptr, nullptr, nullptr, nullptr,
                                           nullptr, nullptr, nullptr);
}

// Round 3
// 294.210 us; speedup vs baseline: 1.3082x; 1.3082x over previous
//
#include <hip/hip_runtime.h>

typedef unsigned short u16;
typedef __bf16 bf16x8_t __attribute__((ext_vector_type(8)));
typedef float f32x4_t __attribute__((ext_vector_type(4)));

#define T_SEQ 4096
#define EMB 512
#define NH 8
#define NKV 2
#define HD 64

__device__ __forceinline__ float bf2f(u16 h) {
    union { unsigned u; float f; } x; x.u = ((unsigned)h) << 16; return x.f;
}
__device__ __forceinline__ u16 f2bf(float f) {
    union { float f; unsigned u; } x; x.f = f;
    unsigned r = x.u + 0x7FFFu + ((x.u >> 16) & 1u);
    return (u16)(r >> 16);
}

// ------------- weight transpose + cast: W[K][N] (f32) -> WT[N][K] (bf16) -------------
__global__ void transpose_kernel(const float* __restrict__ W, u16* __restrict__ WT,
                                 int K, int N) {
    int i = blockIdx.x * 256 + threadIdx.x;
    if (i < K * N) {
        int n = i / K;
        int k = i - n * K;
        WT[i] = f2bf(W[(size_t)k * N + n]);
    }
}

// ------------- x cast: f32 -> bf16, 4 elems/thread -------------
__global__ void cvt_kernel(const float* __restrict__ in, u16* __restrict__ out, int n4) {
    int i = blockIdx.x * 256 + threadIdx.x;
    if (i < n4) {
        float4 v = *reinterpret_cast<const float4*>(in + (size_t)i * 4);
        u16 o[4] = { f2bf(v.x), f2bf(v.y), f2bf(v.z), f2bf(v.w) };
        *reinterpret_cast<uint2*>(out + (size_t)i * 4) = *reinterpret_cast<uint2*>(o);
    }
}

// ------------- RoPE tables: cos/sin[t][j], j<32, fp32 (double trig ~= np ref) -------------
__global__ void rope_table_kernel(float* __restrict__ cost, float* __restrict__ sint) {
    int i = blockIdx.x * 256 + threadIdx.x;   // T_SEQ*32 total
    int t = i >> 5, j = i & 31;
    double invf = pow(1.0e6, -(double)j / 32.0);
    double ang = (double)t * invf;
    cost[i] = (float)cos(ang);
    sint[i] = (float)sin(ang);
}

// ---------------- GEMM: C[M,N] = A[M,K](bf16) @ Bt[N,K](bf16)^T ----------------
template <int EPI>
__global__ __launch_bounds__(256)
void gemm_kernel(const u16* __restrict__ A, const u16* __restrict__ Bt, int K,
                 float* __restrict__ C, int N,
                 const float* __restrict__ bq, const float* __restrict__ bk,
                 const float* __restrict__ bv,
                 const float* __restrict__ cost, const float* __restrict__ sint,
                 u16* __restrict__ qw, u16* __restrict__ kw, u16* __restrict__ vw)
{
    __shared__ __align__(16) u16 As[128][72];
    __shared__ __align__(16) u16 Bs[128][72];

    const int tid  = threadIdx.x;
    const int lane = tid & 63, wave = tid >> 6;
    const int wr = wave >> 1, wc = wave & 1;
    const int tm = blockIdx.x, tn = blockIdx.y;
    const int lrow = lane & 15, lgrp = lane >> 4;

    f32x4_t acc[4][4];
#pragma unroll
    for (int i = 0; i < 4; ++i)
#pragma unroll
        for (int j = 0; j < 4; ++j) acc[i][j] = (f32x4_t){0.f, 0.f, 0.f, 0.f};

    for (int k0 = 0; k0 < K; k0 += 64) {
        __syncthreads();
        {
            const int r0 = tid >> 3;
            const int ko = (tid & 7) * 8;
#pragma unroll
            for (int rr = 0; rr < 4; ++rr) {
                int row = r0 + rr * 32;
                uint4 va = *reinterpret_cast<const uint4*>(A + (size_t)(tm * 128 + row) * K + k0 + ko);
                *reinterpret_cast<uint4*>(&As[row][ko]) = va;
                uint4 vb = *reinterpret_cast<const uint4*>(Bt + (size_t)(tn * 128 + row) * K + k0 + ko);
                *reinterpret_cast<uint4*>(&Bs[row][ko]) = vb;
            }
        }
        __syncthreads();
#pragma unroll
        for (int kc = 0; kc < 2; ++kc) {
            bf16x8_t af[4], bf[4];
#pragma unroll
            for (int mb = 0; mb < 4; ++mb)
                af[mb] = *reinterpret_cast<const bf16x8_t*>(&As[wr * 64 + mb * 16 + lrow][kc * 32 + lgrp * 8]);
#pragma unroll
            for (int nb = 0; nb < 4; ++nb)
                bf[nb] = *reinterpret_cast<const bf16x8_t*>(&Bs[wc * 64 + nb * 16 + lrow][kc * 32 + lgrp * 8]);
#pragma unroll
            for (int mb = 0; mb < 4; ++mb)
#pragma unroll
                for (int nb = 0; nb < 4; ++nb)
                    acc[mb][nb] = __builtin_amdgcn_mfma_f32_16x16x32_bf16(af[mb], bf[nb], acc[mb][nb], 0, 0, 0);
        }
    }

    if (EPI == 0) {
#pragma unroll
        for (int mb = 0; mb < 4; ++mb)
#pragma unroll
            for (int nb = 0; nb < 4; ++nb)
#pragma unroll
                for (int r = 0; r < 4; ++r) {
                    int row = tm * 128 + wr * 64 + mb * 16 + lgrp * 4 + r;
                    int col = tn * 128 + wc * 64 + nb * 16 + lrow;
                    C[(size_t)row * N + col] = acc[mb][nb][r];
                }
    } else {
#pragma unroll
        for (int mb = 0; mb < 4; ++mb)
#pragma unroll
            for (int r = 0; r < 4; ++r) {
                int grow = tm * 128 + wr * 64 + mb * 16 + lgrp * 4 + r;
                int b = grow >> 12, t = grow & 4095;
#pragma unroll
                for (int nb = 0; nb < 2; ++nb) {
                    int n = tn * 128 + wc * 64 + nb * 16 + lrow;
                    int j = n & 63;
                    float c0 = acc[mb][nb][r];
                    float c1 = acc[mb][nb + 2][r];
                    if (n < 512) {               // Q
                        c0 += bq[n]; c1 += bq[n + 32];
                        float cs = cost[t * 32 + j], sn = sint[t * 32 + j];
                        float r0 = c0 * cs - c1 * sn;
                        float r1 = c1 * cs + c0 * sn;
                        r0 *= 0.125f; r1 *= 0.125f;
                        int h = n >> 6;
                        size_t base = ((size_t)(b * NH + h) * T_SEQ + t) * HD;
                        qw[base + j]      = f2bf(r0);
                        qw[base + j + 32] = f2bf(r1);
                    } else if (n < 640) {        // K
                        int nn = n - 512;
                        c0 += bk[nn]; c1 += bk[nn + 32];
                        float cs = cost[t * 32 + j], sn = sint[t * 32 + j];
                        float r0 = c0 * cs - c1 * sn;
                        float r1 = c1 * cs + c0 * sn;
                        int hk2 = nn >> 6;
                        size_t base = ((size_t)(b * NKV + hk2) * T_SEQ + t) * HD;
                        kw[base + j]      = f2bf(r0);
                        kw[base + j + 32] = f2bf(r1);
                    } else {                     // V
                        int nn = n - 640;
                        c0 += bv[nn]; c1 += bv[nn + 32];
                        int hv = nn >> 6;
                        size_t base = ((size_t)(b * NKV + hv) * T_SEQ + t) * HD;
                        vw[base + j]      = f2bf(c0);
                        vw[base + j + 32] = f2bf(c1);
                    }
                }
            }
    }
}

// ---------------- causal flash attention, double-buffered + XOR-swizzled LDS ----------------
// grid: (T/64, B*NH). qt = 63 - blockIdx.x (worst-first). 4 waves, wave w owns q-rows w*16..w*16+15.
// Ks[buf][s][d]: 16B block b of row s stored at block b^(s&7)   -> 2-way reads/writes (free)
// Vs[buf][d][s]: transposed; col s of row d stored at s^(((d&7)^((d>>3)&7))<<3)
//               -> conflict-free transpose writes, 2-way reads
__global__ __launch_bounds__(256)
void attn_kernel(const u16* __restrict__ qw, const u16* __restrict__ kw,
                 const u16* __restrict__ vw, u16* __restrict__ ao)
{
    __shared__ __align__(16) u16 Ks[2][64][64];
    __shared__ __align__(16) u16 Vs[2][64][64];
    __shared__ __align__(16) u16 Ps[64][72];

    const int qt = (gridDim.x - 1) - blockIdx.x;
    const int hdix = blockIdx.y;
    const int b = hdix >> 3, h = hdix & 7, hk = h >> 2;
    const int tid = threadIdx.x, lane = tid & 63, wave = tid >> 6;
    const int lrow = lane & 15, lgrp = lane >> 4;

    const u16* qbase = qw + ((size_t)(b * NH + h) * T_SEQ + qt * 64) * HD;
    const u16* kbase = kw + (size_t)(b * NKV + hk) * T_SEQ * HD;
    const u16* vbase = vw + (size_t)(b * NKV + hk) * T_SEQ * HD;

    // staging geometry: 256 threads, thread covers (s = tid>>3 + 32*rr, 8 d at (tid&7)*8)
    const int ss = tid >> 3;     // 0..31
    const int sb = tid & 7;      // 16B block in row

    bf16x8_t qf[2];
#pragma unroll
    for (int kc = 0; kc < 2; ++kc)
        qf[kc] = *reinterpret_cast<const bf16x8_t*>(qbase + (wave * 16 + lrow) * HD + kc * 32 + lgrp * 8);

    float m[4], l[4];
    f32x4_t o[4];
#pragma unroll
    for (int r = 0; r < 4; ++r) { m[r] = -1e30f; l[r] = 0.f; }
#pragma unroll
    for (int d = 0; d < 4; ++d) o[d] = (f32x4_t){0.f, 0.f, 0.f, 0.f};

    uint4 kr[2], vr[2];

    // ---- prologue: stage tile 0 ----
#pragma unroll
    for (int rr = 0; rr < 2; ++rr) {
        int s = ss + 32 * rr;
        kr[rr] = *reinterpret_cast<const uint4*>(kbase + (size_t)s * HD + sb * 8);
        vr[rr] = *reinterpret_cast<const uint4*>(vbase + (size_t)s * HD + sb * 8);
    }
#pragma unroll
    for (int rr = 0; rr < 2; ++rr) {
        int s = ss + 32 * rr;
        *reinterpret_cast<uint4*>(&Ks[0][s][(sb ^ (s & 7)) << 3]) = kr[rr];
        const u16* pv = reinterpret_cast<const u16*>(&vr[rr]);
#pragma unroll
        for (int jj = 0; jj < 8; ++jj) {
            int d = sb * 8 + jj;
            int fv = jj ^ sb;            // (d&7)^((d>>3)&7)
            Vs[0][d][s ^ (fv << 3)] = pv[jj];
        }
    }
    __syncthreads();

    for (int kt = 0; kt <= qt; ++kt) {
        const int cur = kt & 1;
        const bool pre = (kt < qt);

        // ---- issue next tile's global loads early (latency hides under compute) ----
        if (pre) {
#pragma unroll
            for (int rr = 0; rr < 2; ++rr) {
                int s = ss + 32 * rr;
                kr[rr] = *reinterpret_cast<const uint4*>(kbase + (size_t)((kt + 1) * 64 + s) * HD + sb * 8);
                vr[rr] = *reinterpret_cast<const uint4*>(vbase + (size_t)((kt + 1) * 64 + s) * HD + sb * 8);
            }
        }

        // ---- S = q @ k^T ----
        f32x4_t sacc[4];
#pragma unroll
        for (int kb = 0; kb < 4; ++kb) sacc[kb] = (f32x4_t){0.f, 0.f, 0.f, 0.f};
        __builtin_amdgcn_s_setprio(1);
#pragma unroll
        for (int kc = 0; kc < 2; ++kc)
#pragma unroll
            for (int kb = 0; kb < 4; ++kb) {
                int r = kb * 16 + lrow;
                bf16x8_t kf = *reinterpret_cast<const bf16x8_t*>(
                    &Ks[cur][r][(((kc << 2) + lgrp) ^ (r & 7)) << 3]);
                sacc[kb] = __builtin_amdgcn_mfma_f32_16x16x32_bf16(qf[kc], kf, sacc[kb], 0, 0, 0);
            }
        __builtin_amdgcn_s_setprio(0);

        if (kt == qt) {
#pragma unroll
            for (int kb = 0; kb < 4; ++kb)
#pragma unroll
                for (int r = 0; r < 4; ++r) {
                    int qr = wave * 16 + lgrp * 4 + r;
                    int kc2 = kb * 16 + lrow;
                    if (kc2 > qr) sacc[kb][r] = -1e30f;
                }
        }

        // ---- online softmax (rows in 16-lane groups) ----
        float al[4];
#pragma unroll
        for (int r = 0; r < 4; ++r) {
            float v = fmaxf(fmaxf(sacc[0][r], sacc[1][r]), fmaxf(sacc[2][r], sacc[3][r]));
#pragma unroll
            for (int off = 1; off < 16; off <<= 1) v = fmaxf(v, __shfl_xor(v, off));
            float mn = fmaxf(m[r], v);
            al[r] = __expf(m[r] - mn);
            m[r] = mn;
        }
        float p[4][4];
#pragma unroll
        for (int kb = 0; kb < 4; ++kb)
#pragma unroll
            for (int r = 0; r < 4; ++r) p[kb][r] = __expf(sacc[kb][r] - m[r]);
#pragma unroll
        for (int r = 0; r < 4; ++r) {
            float v = p[0][r] + p[1][r] + p[2][r] + p[3][r];
#pragma unroll
            for (int off = 1; off < 16; off <<= 1) v += __shfl_xor(v, off);
            l[r] = l[r] * al[r] + v;
        }
#pragma unroll
        for (int d = 0; d < 4; ++d)
#pragma unroll
            for (int r = 0; r < 4; ++r) o[d][r] *= al[r];

        // ---- P -> LDS (wave-private rows: NO barrier needed) ----
#pragma unroll
        for (int kb = 0; kb < 4; ++kb)
#pragma unroll
            for (int r = 0; r < 4; ++r)
                Ps[wave * 16 + lgrp * 4 + r][kb * 16 + lrow] = f2bf(p[kb][r]);

        // ---- O += P @ V ----
        __builtin_amdgcn_s_setprio(1);
#pragma unroll
        for (int kc = 0; kc < 2; ++kc) {
            bf16x8_t pf = *reinterpret_cast<const bf16x8_t*>(&Ps[wave * 16 + lrow][kc * 32 + lgrp * 8]);
#pragma unroll
            for (int d = 0; d < 4; ++d) {
                int row = d * 16 + lrow;
                int fv = (row & 7) ^ ((row >> 3) & 7);
                bf16x8_t vf = *reinterpret_cast<const bf16x8_t*>(
                    &Vs[cur][row][(((kc << 2) + lgrp) ^ fv) << 3]);
                o[d] = __builtin_amdgcn_mfma_f32_16x16x32_bf16(pf, vf, o[d], 0, 0, 0);
            }
        }
        __builtin_amdgcn_s_setprio(0);

        // ---- write staged next tile into buf^1, then single barrier ----
        if (pre) {
            const int nxt = cur ^ 1;
#pragma unroll
            for (int rr = 0; rr < 2; ++rr) {
                int s = ss + 32 * rr;
                *reinterpret_cast<uint4*>(&Ks[nxt][s][(sb ^ (s & 7)) << 3]) = kr[rr];
                const u16* pv = reinterpret_cast<const u16*>(&vr[rr]);
#pragma unroll
                for (int jj = 0; jj < 8; ++jj) {
                    int d = sb * 8 + jj;
                    int fv = jj ^ sb;
                    Vs[nxt][d][s ^ (fv << 3)] = pv[jj];
                }
            }
            __syncthreads();
        }
    }

    // epilogue: normalize and store [B,T,H*D] (bf16)
#pragma unroll
    for (int d = 0; d < 4; ++d)
#pragma unroll
        for (int r = 0; r < 4; ++r) {
            int t = qt * 64 + wave * 16 + lgrp * 4 + r;
            float inv = 1.0f / l[r];
            ao[((size_t)(b * T_SEQ) + t) * EMB + h * HD + d * 16 + lrow] = f2bf(o[d][r] * inv);
        }
}

// ---------------- launch ----------------
extern "C" void kernel_launch(void* const* d_in, const int* in_sizes, int n_in,
                              void* d_out, int out_size, void* d_ws, size_t ws_size,
                              hipStream_t stream)
{
    const float* x  = (const float*)d_in[0];
    const float* Wq = (const float*)d_in[1];
    const float* bq = (const float*)d_in[2];
    const float* Wk = (const float*)d_in[3];
    const float* bk = (const float*)d_in[4];
    const float* Wv = (const float*)d_in[5];
    const float* bv = (const float*)d_in[6];
    const float* Wo = (const float*)d_in[7];
    float* out = (float*)d_out;

    char* ws = (char*)d_ws;
    u16*   WqkvT = (u16*)(ws);                  // [768][512] bf16
    u16*   WoT   = (u16*)(ws + 786432);         // [512][512] bf16
    float* cost  = (float*)(ws + 1310720);      // [4096][32] f32
    float* sint  = (float*)(ws + 1835008);      // [4096][32] f32
    u16*   xbf   = (u16*)(ws + 2359296);        // [8192][512] bf16
    u16*   qw    = (u16*)(ws + 10747904);       // [2][8][4096][64] bf16 (pre-scaled)
    u16*   kw    = (u16*)(ws + 19136512);       // [2][2][4096][64] bf16
    u16*   vw    = (u16*)(ws + 21233664);       // [2][2][4096][64] bf16
    u16*   ao    = (u16*)(ws + 23330816);       // [8192][512] bf16

    transpose_kernel<<<(512 * 512 + 255) / 256, 256, 0, stream>>>(Wq, WqkvT, 512, 512);
    transpose_kernel<<<(512 * 128 + 255) / 256, 256, 0, stream>>>(Wk, WqkvT + 512 * 512, 512, 128);
    transpose_kernel<<<(512 * 128 + 255) / 256, 256, 0, stream>>>(Wv, WqkvT + 640 * 512, 512, 128);
    transpose_kernel<<<(512 * 512 + 255) / 256, 256, 0, stream>>>(Wo, WoT, 512, 512);
    cvt_kernel<<<(2 * T_SEQ * EMB / 4 + 255) / 256, 256, 0, stream>>>(x, xbf, 2 * T_SEQ * EMB / 4);
    rope_table_kernel<<<(T_SEQ * 32) / 256, 256, 0, stream>>>(cost, sint);

    dim3 gp(64, 6);
    gemm_kernel<1><<<gp, 256, 0, stream>>>(xbf, WqkvT, 512, nullptr, 768,
                                           bq, bk, bv, cost, sint, qw, kw, vw);

    dim3 ga(T_SEQ / 64, 2 * NH);
    attn_kernel<<<ga, 256, 0, stream>>>(qw, kw, vw, ao);

    dim3 go(64, 4);
    gemm_kernel<0><<<go, 256, 0, stream>>>(ao, WoT, 512, out, 512,
                                           nullptr, nullptr, nullptr, nullptr, nullptr,
                                           nullptr, nullptr, nullptr);
}